// Round 10
// baseline (405.602 us; speedup 1.0000x reference)
//
#include <hip/hip_runtime.h>

#define N_NODES 50000
#define N_EDGES 800000
#define HID 128
#define SLOT (N_NODES * HID)          // 6,400,000 floats per output block
#define W_STRIDE (HID * HID)          // 16384
#define NCHUNK 98                     // ceil(50000/512) scan chunks

typedef float f32x4 __attribute__((ext_vector_type(4)));

// ---------------- workspace layout (byte offsets, 512-aligned) ----------------
#define OFF_CNT    0ul                      // 50000*4
#define OFF_DINV   200192ul                 // 50000*4
#define OFF_RPTR   400384ul                 // 50001*4
#define OFF_RFILL  600576ul                 // 50000*4
#define OFF_BSUM   800768ul                 // 256*4
#define OFF_SRCS   802816ul                 // 800000*4
#define OFF_H_WS   4002816ul                // 50000*128*4 (optional)

// ---------------- preprocessing kernels ----------------

__global__ void k_count(const int* __restrict__ ei, int* __restrict__ cnt) {
    int e = blockIdx.x * blockDim.x + threadIdx.x;
    if (e < N_EDGES) atomicAdd(&cnt[ei[N_EDGES + e]], 1);
}

__global__ void k_scan_block(const int* __restrict__ cnt, int* __restrict__ rptr,
                             int* __restrict__ bsum) {
    __shared__ int s[512];
    int tid = threadIdx.x;
    int gid = blockIdx.x * 512 + tid;
    int v = (gid < N_NODES) ? cnt[gid] : 0;
    s[tid] = v;
    __syncthreads();
    for (int off = 1; off < 512; off <<= 1) {
        int t = (tid >= off) ? s[tid - off] : 0;
        __syncthreads();
        s[tid] += t;
        __syncthreads();
    }
    if (gid < N_NODES) rptr[gid] = s[tid] - v;   // chunk-local exclusive
    if (tid == 511) bsum[blockIdx.x] = s[511];
}

// finalize: each block redundantly scans the 98 chunk sums in LDS (1 µs),
// then applies offset + writes rfill + dinv. Replaces scan_sums+scan_add.
__global__ void k_scan_add(int* __restrict__ rptr, int* __restrict__ rfill,
                           const int* __restrict__ bsum, const int* __restrict__ cnt,
                           float* __restrict__ dinv) {
    __shared__ int sb[128];
    int tid = threadIdx.x;
    if (tid < 128) sb[tid] = (tid < NCHUNK) ? bsum[tid] : 0;
    __syncthreads();
    for (int off = 1; off < 128; off <<= 1) {
        int t = (tid < 128 && tid >= off) ? sb[tid - off] : 0;
        __syncthreads();
        if (tid < 128) sb[tid] += t;               // inclusive scan
        __syncthreads();
    }
    int gid = blockIdx.x * blockDim.x + tid;
    if (gid < N_NODES) {
        int chunk = gid >> 9;
        int base  = (chunk == 0) ? 0 : sb[chunk - 1];
        int r = rptr[gid] + base;
        rptr[gid]  = r;
        rfill[gid] = r;
        int c = cnt[gid];
        dinv[gid] = (c > 0) ? rsqrtf((float)c) : 0.0f;
    }
    if (gid == 0) rptr[N_NODES] = N_EDGES;
}

__global__ void k_scatter(const int* __restrict__ ei, int* __restrict__ rfill,
                          int* __restrict__ srcs) {
    int e = blockIdx.x * blockDim.x + threadIdx.x;
    if (e < N_EDGES) {
        int sv = ei[e];
        int d  = ei[N_EDGES + e];
        int pos = atomicAdd(&rfill[d], 1);
        srcs[pos] = sv;
    }
}

__global__ void k_copy(const float* __restrict__ src, float* __restrict__ dst, int n4) {
    int i = blockIdx.x * blockDim.x + threadIdx.x;
    if (i < n4) ((float4*)dst)[i] = ((const float4*)src)[i];
}

// ---------------- dense transform: H = (X @ W) * dinv[row] ----------------
// 64-row x 64-col tile; W panel (128x64, 32 KB) staged once per block;
// X tile (64x128, 32 KB) XOR-swizzled. 64 KB LDS -> 2 blocks/CU.
// copy_out (layer 1 only): chalf==0 blocks write-through the staged X rows
// to embeddings[0] (saves the standalone copy's 25.6 MB re-read of x).
__launch_bounds__(256, 2)
__global__ void k_gemm_scale(const float* __restrict__ X, const float* __restrict__ W,
                             const float* __restrict__ dinv, float* __restrict__ H,
                             float* __restrict__ copy_out) {
    __shared__ float sW[HID * 64];
    __shared__ float sX[64 * HID];
    int tid   = threadIdx.x;
    int chalf = blockIdx.x & 1;
    int row0  = (blockIdx.x >> 1) * 64;

    const float4* W4  = (const float4*)W;
    float4*       sW4 = (float4*)sW;
    for (int j = tid; j < 2048; j += 256) {
        int k  = j >> 4;
        int c4 = j & 15;
        sW4[j] = W4[k * 32 + chalf * 16 + c4];
    }

    const float4* X4  = (const float4*)X;
    float4*       sX4 = (float4*)sX;
    bool do_copy = (copy_out != nullptr) && (chalf == 0);
    for (int j = tid; j < 2048; j += 256) {
        int r   = j >> 5;
        int c4  = j & 31;
        int row = row0 + r;
        float4 v = {0.f, 0.f, 0.f, 0.f};
        if (row < N_NODES) {
            v = X4[row * 32 + c4];
            if (do_copy)
                __builtin_nontemporal_store(*(const f32x4*)&v,
                                            (f32x4*)&((float4*)copy_out)[row * 32 + c4]);
        }
        sX4[r * 32 + (c4 ^ ((r >> 3) & 7))] = v;
    }
    __syncthreads();

    int ty  = tid >> 4;
    int tx  = tid & 15;
    int swz = (ty >> 1) & 7;

    float4 acc[4];
    #pragma unroll
    for (int r = 0; r < 4; ++r) acc[r] = {0.f, 0.f, 0.f, 0.f};

    #pragma unroll 4
    for (int k0 = 0; k0 < HID; k0 += 4) {
        int k4 = k0 >> 2;
        float4 wv[4];
        #pragma unroll
        for (int kk = 0; kk < 4; ++kk)
            wv[kk] = sW4[(k0 + kk) * 16 + tx];
        float4 xv[4];
        #pragma unroll
        for (int r = 0; r < 4; ++r)
            xv[r] = sX4[(ty * 4 + r) * 32 + (k4 ^ swz)];
        #pragma unroll
        for (int r = 0; r < 4; ++r) {
            float xk0 = xv[r].x, xk1 = xv[r].y, xk2 = xv[r].z, xk3 = xv[r].w;
            acc[r].x += xk0 * wv[0].x + xk1 * wv[1].x + xk2 * wv[2].x + xk3 * wv[3].x;
            acc[r].y += xk0 * wv[0].y + xk1 * wv[1].y + xk2 * wv[2].y + xk3 * wv[3].y;
            acc[r].z += xk0 * wv[0].z + xk1 * wv[1].z + xk2 * wv[2].z + xk3 * wv[3].z;
            acc[r].w += xk0 * wv[0].w + xk1 * wv[1].w + xk2 * wv[2].w + xk3 * wv[3].w;
        }
    }

    float4* H4 = (float4*)H;
    #pragma unroll
    for (int r = 0; r < 4; ++r) {
        int row = row0 + ty * 4 + r;
        if (row < N_NODES) {
            float dv = dinv[row];
            float4 o = acc[r];
            o.x *= dv; o.y *= dv; o.z *= dv; o.w *= dv;
            H4[row * 32 + chalf * 16 + tx] = o;   // re-read by agg: keep cached
        }
    }
}

// ---------------- aggregation: out[v] = dinv[v] * sum_{src in row v} H[src] + b ----
// Two nodes per wave (half-wave each), one float4 column per lane, one full
// 512 B row gather per edge instruction, 4-deep unroll. Output stores are
// NON-TEMPORAL: streaming writes never re-read in-dispatch; keeping them out
// of L2 preserves capacity for gathered h rows (raises L2 hit on the gather).
// NOTE: out0/out1 must NOT alias H.
__global__ void k_agg(const float* __restrict__ H, const int* __restrict__ rptr,
                      const int* __restrict__ srcs, const float* __restrict__ dinv,
                      const float* __restrict__ bias, float* __restrict__ out0,
                      float* __restrict__ out1) {
    int pair = (blockIdx.x * blockDim.x + threadIdx.x) >> 6;   // wave index
    int lane = threadIdx.x & 63;
    int wid  = pair * 2 + (lane >> 5);     // this half-wave's node
    int l32  = lane & 31;                  // float4 column owned by this lane
    if (wid >= N_NODES) return;

    int beg = rptr[wid];
    int end = rptr[wid + 1];

    const float4* H4 = (const float4*)H;

    float4 a0 = {0.f,0.f,0.f,0.f}, a1 = {0.f,0.f,0.f,0.f};
    float4 a2 = {0.f,0.f,0.f,0.f}, a3 = {0.f,0.f,0.f,0.f};

    int p  = beg;
    int n4 = beg + ((end - beg) & ~3);
    for (; p < n4; p += 4) {
        int s0 = srcs[p + 0];
        int s1 = srcs[p + 1];
        int s2 = srcs[p + 2];
        int s3 = srcs[p + 3];
        float4 h0 = H4[s0 * 32 + l32];
        float4 h1 = H4[s1 * 32 + l32];
        float4 h2 = H4[s2 * 32 + l32];
        float4 h3 = H4[s3 * 32 + l32];
        a0.x += h0.x; a0.y += h0.y; a0.z += h0.z; a0.w += h0.w;
        a1.x += h1.x; a1.y += h1.y; a1.z += h1.z; a1.w += h1.w;
        a2.x += h2.x; a2.y += h2.y; a2.z += h2.z; a2.w += h2.w;
        a3.x += h3.x; a3.y += h3.y; a3.z += h3.z; a3.w += h3.w;
    }
    for (; p < end; ++p) {
        float4 hv = H4[srcs[p] * 32 + l32];
        a0.x += hv.x; a0.y += hv.y; a0.z += hv.z; a0.w += hv.w;
    }

    float dv  = dinv[wid];
    float4 bb = ((const float4*)bias)[l32];
    float4 res;
    res.x = (a0.x + a1.x + a2.x + a3.x) * dv + bb.x;
    res.y = (a0.y + a1.y + a2.y + a3.y) * dv + bb.y;
    res.z = (a0.z + a1.z + a2.z + a3.z) * dv + bb.z;
    res.w = (a0.w + a1.w + a2.w + a3.w) * dv + bb.w;

    __builtin_nontemporal_store(*(const f32x4*)&res, (f32x4*)&((float4*)out0)[wid * 32 + l32]);
    if (out1)
        __builtin_nontemporal_store(*(const f32x4*)&res, (f32x4*)&((float4*)out1)[wid * 32 + l32]);
}

// ---------------- launch ----------------

extern "C" void kernel_launch(void* const* d_in, const int* in_sizes, int n_in,
                              void* d_out, int out_size, void* d_ws, size_t ws_size,
                              hipStream_t stream) {
    const float* x  = (const float*)d_in[0];
    const int*   ei = (const int*)d_in[1];
    const float* Ws = (const float*)d_in[2];
    const float* bs = (const float*)d_in[3];
    float* out = (float*)d_out;
    char*  ws  = (char*)d_ws;

    int*   cnt   = (int*)  (ws + OFF_CNT);
    float* dinv  = (float*)(ws + OFF_DINV);
    int*   rptr  = (int*)  (ws + OFF_RPTR);
    int*   rfill = (int*)  (ws + OFF_RFILL);
    int*   bsum  = (int*)  (ws + OFF_BSUM);
    int*   srcs  = (int*)  (ws + OFF_SRCS);

    // output slots: [0]=x3(final), [1]=x0, [2]=x1, [3]=x2, [4]=x3
    float* slot0 = out;
    float* slot1 = out + 1l * SLOT;
    float* slot2 = out + 2l * SLOT;
    float* slot3 = out + 3l * SLOT;
    float* slot4 = out + 4l * SLOT;

    bool   h_in_ws = ws_size >= (size_t)(OFF_H_WS + (size_t)SLOT * 4);
    float* h = h_in_ws ? (float*)(ws + OFF_H_WS) : slot0;

    const int NB_NODE = (N_NODES + 255) / 256;   // 196
    const int NB_EDGE = (N_EDGES + 255) / 256;   // 3125
    const int NB_SCAN = (N_NODES + 511) / 512;   // 98

    // ---- preprocessing: degrees, CSR by dst, dinv (5 dispatches) ----
    hipMemsetAsync(cnt, 0, N_NODES * sizeof(int), stream);
    k_count     <<<NB_EDGE, 256, 0, stream>>>(ei, cnt);
    k_scan_block<<<NB_SCAN, 512, 0, stream>>>(cnt, rptr, bsum);
    k_scan_add  <<<NB_NODE, 256, 0, stream>>>(rptr, rfill, bsum, cnt, dinv);
    k_scatter   <<<NB_EDGE, 256, 0, stream>>>(ei, rfill, srcs);

    const int NB_GEMM = 2 * ((N_NODES + 63) / 64);   // 1564
    const int NB_AGG  = (N_NODES / 2 + 3) / 4;       // 6250 (2 nodes/wave)

    // ---- layer 1 (gemm also write-throughs x -> embeddings[0]) ----
    k_gemm_scale<<<NB_GEMM, 256, 0, stream>>>(x, Ws + 0 * W_STRIDE, dinv, h, slot1);
    k_agg       <<<NB_AGG, 256, 0, stream>>>(h, rptr, srcs, dinv, bs + 0 * HID, slot2, nullptr);

    // ---- layer 2 ----
    k_gemm_scale<<<NB_GEMM, 256, 0, stream>>>(slot2, Ws + 1 * W_STRIDE, dinv, h, nullptr);
    k_agg       <<<NB_AGG, 256, 0, stream>>>(h, rptr, srcs, dinv, bs + 1 * HID, slot3, nullptr);

    // ---- layer 3 ----
    k_gemm_scale<<<NB_GEMM, 256, 0, stream>>>(slot3, Ws + 2 * W_STRIDE, dinv, h, nullptr);
    if (h_in_ws) {
        k_agg<<<NB_AGG, 256, 0, stream>>>(h, rptr, srcs, dinv, bs + 2 * HID, slot4, slot0);
    } else {
        k_agg<<<NB_AGG, 256, 0, stream>>>(h, rptr, srcs, dinv, bs + 2 * HID, slot4, nullptr);
        k_copy<<<SLOT / 4 / 256, 256, 0, stream>>>(slot4, slot0, SLOT / 4);
    }
}

// Round 11
// 394.802 us; speedup vs baseline: 1.0274x; 1.0274x over previous
//
#include <hip/hip_runtime.h>

#define N_NODES 50000
#define N_EDGES 800000
#define HID 128
#define SLOT (N_NODES * HID)          // 6,400,000 floats per output block
#define W_STRIDE (HID * HID)          // 16384
#define NCHUNK 98                     // ceil(50000/512) scan chunks

// ---------------- workspace layout (byte offsets, 512-aligned) ----------------
#define OFF_CNT    0ul                      // 50000*4
#define OFF_DINV   200192ul                 // 50000*4
#define OFF_RPTR   400384ul                 // 50001*4
#define OFF_RFILL  600576ul                 // 50000*4
#define OFF_BSUM   800768ul                 // 256*4
#define OFF_SRCS   802816ul                 // 800000*4
#define OFF_H_WS   4002816ul                // 50000*128*4 (optional)

// ---------------- preprocessing kernels ----------------

// degree count + x -> slot1 copy fused (independent work hides under atomics)
__global__ void k_count(const int* __restrict__ ei, int* __restrict__ cnt,
                        const float* __restrict__ x, float* __restrict__ slot1) {
    int g = blockIdx.x * blockDim.x + threadIdx.x;
    if (g < N_EDGES) atomicAdd(&cnt[ei[N_EDGES + g]], 1);
    const float4* x4  = (const float4*)x;
    float4*       s14 = (float4*)slot1;
    int gs = gridDim.x * blockDim.x;
    for (int i = g; i < SLOT / 4; i += gs) s14[i] = x4[i];
}

__global__ void k_scan_block(const int* __restrict__ cnt, int* __restrict__ rptr,
                             int* __restrict__ bsum) {
    __shared__ int s[512];
    int tid = threadIdx.x;
    int gid = blockIdx.x * 512 + tid;
    int v = (gid < N_NODES) ? cnt[gid] : 0;
    s[tid] = v;
    __syncthreads();
    for (int off = 1; off < 512; off <<= 1) {
        int t = (tid >= off) ? s[tid - off] : 0;
        __syncthreads();
        s[tid] += t;
        __syncthreads();
    }
    if (gid < N_NODES) rptr[gid] = s[tid] - v;   // chunk-local exclusive
    if (tid == 511) bsum[blockIdx.x] = s[511];
}

// finalize: each block redundantly scans the 98 chunk sums in LDS (~1 µs),
// then applies offset + writes rfill + dinv. (merged scan_sums+scan_add)
__global__ void k_scan_add(int* __restrict__ rptr, int* __restrict__ rfill,
                           const int* __restrict__ bsum, const int* __restrict__ cnt,
                           float* __restrict__ dinv) {
    __shared__ int sb[128];
    int tid = threadIdx.x;
    if (tid < 128) sb[tid] = (tid < NCHUNK) ? bsum[tid] : 0;
    __syncthreads();
    for (int off = 1; off < 128; off <<= 1) {
        int t = (tid < 128 && tid >= off) ? sb[tid - off] : 0;
        __syncthreads();
        if (tid < 128) sb[tid] += t;               // inclusive scan
        __syncthreads();
    }
    int gid = blockIdx.x * blockDim.x + tid;
    if (gid < N_NODES) {
        int chunk = gid >> 9;
        int base  = (chunk == 0) ? 0 : sb[chunk - 1];
        int r = rptr[gid] + base;
        rptr[gid]  = r;
        rfill[gid] = r;
        int c = cnt[gid];
        dinv[gid] = (c > 0) ? rsqrtf((float)c) : 0.0f;
    }
    if (gid == 0) rptr[N_NODES] = N_EDGES;
}

__global__ void k_scatter(const int* __restrict__ ei, int* __restrict__ rfill,
                          int* __restrict__ srcs) {
    int e = blockIdx.x * blockDim.x + threadIdx.x;
    if (e < N_EDGES) {
        int sv = ei[e];
        int d  = ei[N_EDGES + e];
        int pos = atomicAdd(&rfill[d], 1);
        srcs[pos] = sv;
    }
}

__global__ void k_copy(const float* __restrict__ src, float* __restrict__ dst, int n4) {
    int i = blockIdx.x * blockDim.x + threadIdx.x;
    if (i < n4) ((float4*)dst)[i] = ((const float4*)src)[i];
}

// ---------------- dense transform: H = (X @ W) * dinv[row] ----------------
// 64-row x 64-col tile; W panel (128x64, 32 KB) staged once per block and
// reused over all k-steps; X tile (64x128, 32 KB) XOR-swizzled.
// 64 KB LDS -> 2 blocks/CU. (round-6 verified; near the 10.4 µs FLOP floor)
__launch_bounds__(256, 2)
__global__ void k_gemm_scale(const float* __restrict__ X, const float* __restrict__ W,
                             const float* __restrict__ dinv, float* __restrict__ H) {
    __shared__ float sW[HID * 64];
    __shared__ float sX[64 * HID];
    int tid   = threadIdx.x;
    int chalf = blockIdx.x & 1;
    int row0  = (blockIdx.x >> 1) * 64;

    const float4* W4  = (const float4*)W;
    float4*       sW4 = (float4*)sW;
    for (int j = tid; j < 2048; j += 256) {
        int k  = j >> 4;
        int c4 = j & 15;
        sW4[j] = W4[k * 32 + chalf * 16 + c4];
    }

    const float4* X4  = (const float4*)X;
    float4*       sX4 = (float4*)sX;
    for (int j = tid; j < 2048; j += 256) {
        int r   = j >> 5;
        int c4  = j & 31;
        int row = row0 + r;
        float4 v = {0.f, 0.f, 0.f, 0.f};
        if (row < N_NODES) v = X4[row * 32 + c4];
        sX4[r * 32 + (c4 ^ ((r >> 3) & 7))] = v;
    }
    __syncthreads();

    int ty  = tid >> 4;
    int tx  = tid & 15;
    int swz = (ty >> 1) & 7;

    float4 acc[4];
    #pragma unroll
    for (int r = 0; r < 4; ++r) acc[r] = {0.f, 0.f, 0.f, 0.f};

    #pragma unroll 4
    for (int k0 = 0; k0 < HID; k0 += 4) {
        int k4 = k0 >> 2;
        float4 wv[4];
        #pragma unroll
        for (int kk = 0; kk < 4; ++kk)
            wv[kk] = sW4[(k0 + kk) * 16 + tx];
        float4 xv[4];
        #pragma unroll
        for (int r = 0; r < 4; ++r)
            xv[r] = sX4[(ty * 4 + r) * 32 + (k4 ^ swz)];
        #pragma unroll
        for (int r = 0; r < 4; ++r) {
            float xk0 = xv[r].x, xk1 = xv[r].y, xk2 = xv[r].z, xk3 = xv[r].w;
            acc[r].x += xk0 * wv[0].x + xk1 * wv[1].x + xk2 * wv[2].x + xk3 * wv[3].x;
            acc[r].y += xk0 * wv[0].y + xk1 * wv[1].y + xk2 * wv[2].y + xk3 * wv[3].y;
            acc[r].z += xk0 * wv[0].z + xk1 * wv[1].z + xk2 * wv[2].z + xk3 * wv[3].z;
            acc[r].w += xk0 * wv[0].w + xk1 * wv[1].w + xk2 * wv[2].w + xk3 * wv[3].w;
        }
    }

    float4* H4 = (float4*)H;
    #pragma unroll
    for (int r = 0; r < 4; ++r) {
        int row = row0 + ty * 4 + r;
        if (row < N_NODES) {
            float dv = dinv[row];
            float4 o = acc[r];
            o.x *= dv; o.y *= dv; o.z *= dv; o.w *= dv;
            H4[row * 32 + chalf * 16 + tx] = o;
        }
    }
}

// ---------------- aggregation: out[v] = dinv[v] * sum_{src in row v} H[src] + b ----
// Two nodes per wave (half-wave each), one float4 column per lane, one full
// 512 B row gather per edge instruction, 4-deep unroll (8 rows in flight).
// Regular (cached) stores: outputs are the next layer's GEMM input — NT
// stores here cost ~10 µs/layer in HBM refetch (round-10 lesson).
// NOTE: out0/out1 must NOT alias H.
__global__ void k_agg(const float* __restrict__ H, const int* __restrict__ rptr,
                      const int* __restrict__ srcs, const float* __restrict__ dinv,
                      const float* __restrict__ bias, float* __restrict__ out0,
                      float* __restrict__ out1) {
    int pair = (blockIdx.x * blockDim.x + threadIdx.x) >> 6;   // wave index
    int lane = threadIdx.x & 63;
    int wid  = pair * 2 + (lane >> 5);     // this half-wave's node
    int l32  = lane & 31;                  // float4 column owned by this lane
    if (wid >= N_NODES) return;

    int beg = rptr[wid];
    int end = rptr[wid + 1];

    const float4* H4 = (const float4*)H;

    float4 a0 = {0.f,0.f,0.f,0.f}, a1 = {0.f,0.f,0.f,0.f};
    float4 a2 = {0.f,0.f,0.f,0.f}, a3 = {0.f,0.f,0.f,0.f};

    int p  = beg;
    int n4 = beg + ((end - beg) & ~3);
    for (; p < n4; p += 4) {
        int s0 = srcs[p + 0];
        int s1 = srcs[p + 1];
        int s2 = srcs[p + 2];
        int s3 = srcs[p + 3];
        float4 h0 = H4[s0 * 32 + l32];
        float4 h1 = H4[s1 * 32 + l32];
        float4 h2 = H4[s2 * 32 + l32];
        float4 h3 = H4[s3 * 32 + l32];
        a0.x += h0.x; a0.y += h0.y; a0.z += h0.z; a0.w += h0.w;
        a1.x += h1.x; a1.y += h1.y; a1.z += h1.z; a1.w += h1.w;
        a2.x += h2.x; a2.y += h2.y; a2.z += h2.z; a2.w += h2.w;
        a3.x += h3.x; a3.y += h3.y; a3.z += h3.z; a3.w += h3.w;
    }
    for (; p < end; ++p) {
        float4 hv = H4[srcs[p] * 32 + l32];
        a0.x += hv.x; a0.y += hv.y; a0.z += hv.z; a0.w += hv.w;
    }

    float dv  = dinv[wid];
    float4 bb = ((const float4*)bias)[l32];
    float4 res;
    res.x = (a0.x + a1.x + a2.x + a3.x) * dv + bb.x;
    res.y = (a0.y + a1.y + a2.y + a3.y) * dv + bb.y;
    res.z = (a0.z + a1.z + a2.z + a3.z) * dv + bb.z;
    res.w = (a0.w + a1.w + a2.w + a3.w) * dv + bb.w;
    ((float4*)out0)[wid * 32 + l32] = res;
    if (out1) ((float4*)out1)[wid * 32 + l32] = res;
}

// ---------------- launch ----------------

extern "C" void kernel_launch(void* const* d_in, const int* in_sizes, int n_in,
                              void* d_out, int out_size, void* d_ws, size_t ws_size,
                              hipStream_t stream) {
    const float* x  = (const float*)d_in[0];
    const int*   ei = (const int*)d_in[1];
    const float* Ws = (const float*)d_in[2];
    const float* bs = (const float*)d_in[3];
    float* out = (float*)d_out;
    char*  ws  = (char*)d_ws;

    int*   cnt   = (int*)  (ws + OFF_CNT);
    float* dinv  = (float*)(ws + OFF_DINV);
    int*   rptr  = (int*)  (ws + OFF_RPTR);
    int*   rfill = (int*)  (ws + OFF_RFILL);
    int*   bsum  = (int*)  (ws + OFF_BSUM);
    int*   srcs  = (int*)  (ws + OFF_SRCS);

    // output slots: [0]=x3(final), [1]=x0, [2]=x1, [3]=x2, [4]=x3
    float* slot0 = out;
    float* slot1 = out + 1l * SLOT;
    float* slot2 = out + 2l * SLOT;
    float* slot3 = out + 3l * SLOT;
    float* slot4 = out + 4l * SLOT;

    bool   h_in_ws = ws_size >= (size_t)(OFF_H_WS + (size_t)SLOT * 4);
    float* h = h_in_ws ? (float*)(ws + OFF_H_WS) : slot0;

    const int NB_NODE = (N_NODES + 255) / 256;   // 196
    const int NB_EDGE = (N_EDGES + 255) / 256;   // 3125
    const int NB_SCAN = (N_NODES + 511) / 512;   // 98

    // ---- preprocessing: degrees(+x copy), CSR by dst, dinv ----
    hipMemsetAsync(cnt, 0, N_NODES * sizeof(int), stream);
    k_count     <<<NB_EDGE, 256, 0, stream>>>(ei, cnt, x, slot1);
    k_scan_block<<<NB_SCAN, 512, 0, stream>>>(cnt, rptr, bsum);
    k_scan_add  <<<NB_NODE, 256, 0, stream>>>(rptr, rfill, bsum, cnt, dinv);
    k_scatter   <<<NB_EDGE, 256, 0, stream>>>(ei, rfill, srcs);

    const int NB_GEMM = 2 * ((N_NODES + 63) / 64);   // 1564
    const int NB_AGG  = (N_NODES / 2 + 3) / 4;       // 6250 (2 nodes/wave)

    // ---- layer 1 ----
    k_gemm_scale<<<NB_GEMM, 256, 0, stream>>>(x, Ws + 0 * W_STRIDE, dinv, h);
    k_agg       <<<NB_AGG, 256, 0, stream>>>(h, rptr, srcs, dinv, bs + 0 * HID, slot2, nullptr);

    // ---- layer 2 ----
    k_gemm_scale<<<NB_GEMM, 256, 0, stream>>>(slot2, Ws + 1 * W_STRIDE, dinv, h);
    k_agg       <<<NB_AGG, 256, 0, stream>>>(h, rptr, srcs, dinv, bs + 1 * HID, slot3, nullptr);

    // ---- layer 3 ----
    k_gemm_scale<<<NB_GEMM, 256, 0, stream>>>(slot3, Ws + 2 * W_STRIDE, dinv, h);
    if (h_in_ws) {
        k_agg<<<NB_AGG, 256, 0, stream>>>(h, rptr, srcs, dinv, bs + 2 * HID, slot4, slot0);
    } else {
        k_agg<<<NB_AGG, 256, 0, stream>>>(h, rptr, srcs, dinv, bs + 2 * HID, slot4, nullptr);
        k_copy<<<SLOT / 4 / 256, 256, 0, stream>>>(slot4, slot0, SLOT / 4);
    }
}